// Round 5
// baseline (1190.910 us; speedup 1.0000x reference)
//
#include <hip/hip_runtime.h>
#include <math.h>

// ---------------------------------------------------------------------------
// GCN forward, numerically matched to the numpy float32 reference:
//  - GEMMs: per-element sequential-k fp32 FMA chain (== BLAS sgemm microkernel)
//  - segment_sum: per-feature fp32 adds in ascending-edge order (== np.add.at)
//  - head final dot: f64 (no downstream amplification)
// NUMERICS ARE LOCKED (absmax 1e-13 since round 3): only scheduling/memory
// layout may change between rounds, never the fp32 op order.
//
// CSR build = deterministic stable LSD radix sort by dst (16-bit key, 2x8-bit
// passes), payload src. Stability over edge index => ascending-edge order per
// node with NO order-dependent atomics.  (Round-4 fill_kernel: 139us, 102MB
// write-amp from 4B scatters; radix scatter writes ~16-record runs/digit.)
// ---------------------------------------------------------------------------

typedef unsigned long long u64;

#define RB_SIZE   4096
#define RB_ROUNDS 16   // RB_SIZE / 256

__global__ __launch_bounds__(256) void zero_kernel(int* __restrict__ p, int n) {
    int i = blockIdx.x * 256 + threadIdx.x;
    if (i < n) p[i] = 0;
}

__global__ __launch_bounds__(256) void hist_kernel(const int* __restrict__ dst,
                                                   int* __restrict__ counts, int E) {
    int e = blockIdx.x * 256 + threadIdx.x;
    if (e < E) atomicAdd(&counts[dst[e]], 1);
}

// --- hierarchical exclusive scan over counts[n] -> offs[n+1] ---------------
__global__ __launch_bounds__(1024) void scan_part(const int* __restrict__ counts,
                                                  int* __restrict__ bsum, int n) {
    __shared__ int red[1024];
    int i = blockIdx.x * 1024 + threadIdx.x;
    red[threadIdx.x] = (i < n) ? counts[i] : 0;
    __syncthreads();
    for (int d = 512; d; d >>= 1) {
        if (threadIdx.x < d) red[threadIdx.x] += red[threadIdx.x + d];
        __syncthreads();
    }
    if (threadIdx.x == 0) bsum[blockIdx.x] = red[0];
}

__global__ void scan_tops(const int* __restrict__ bsum, int* __restrict__ bbase,
                          int nb, int* __restrict__ offs, int n) {
    if (threadIdx.x == 0) {
        int run = 0;
        for (int b = 0; b < nb; ++b) { bbase[b] = run; run += bsum[b]; }
        offs[n] = run;
    }
}

__global__ __launch_bounds__(1024) void scan_final(const int* __restrict__ counts,
                                                   const int* __restrict__ bbase,
                                                   int* __restrict__ offs, int n) {
    __shared__ int buf[1024];
    int tid = threadIdx.x;
    int i = blockIdx.x * 1024 + tid;
    int c = (i < n) ? counts[i] : 0;
    buf[tid] = c;
    __syncthreads();
    for (int d = 1; d < 1024; d <<= 1) {
        int v = (tid >= d) ? buf[tid - d] : 0;
        __syncthreads();
        buf[tid] += v;
        __syncthreads();
    }
    if (i < n) offs[i] = bbase[blockIdx.x] + buf[tid] - c;
}

// --- radix pass kernels ----------------------------------------------------
// FIRST pass: key = dst & 255, input = raw dst/src arrays, output = u64 records
//             rec = (src << 32) | dst.
// SECOND pass: key = (dst >> 8) & 255 from records, output = src into csr_src.
template <bool FIRST>
__global__ __launch_bounds__(256) void radix_hist(const int* __restrict__ dstArr,
                                                  const u64* __restrict__ recIn,
                                                  int* __restrict__ blockhist,
                                                  int E, int NBLK) {
    __shared__ int cnt[256];
    cnt[threadIdx.x] = 0;
    __syncthreads();
    int base = blockIdx.x * RB_SIZE;
    for (int t = threadIdx.x; t < RB_SIZE; t += 256) {
        int i = base + t;
        if (i < E) {
            int d = FIRST ? (dstArr[i] & 255)
                          : (int)((recIn[i] >> 8) & 255);
            atomicAdd(&cnt[d], 1);
        }
    }
    __syncthreads();
    blockhist[threadIdx.x * NBLK + blockIdx.x] = cnt[threadIdx.x];
}

// single block, 256 threads: thread d owns digit d
__global__ __launch_bounds__(256) void radix_scan(const int* __restrict__ blockhist,
                                                  int* __restrict__ blockbase, int NBLK) {
    int d = threadIdx.x;
    int run = 0;
    for (int b = 0; b < NBLK; ++b) {
        blockbase[d * NBLK + b] = run;
        run += blockhist[d * NBLK + b];
    }
    __shared__ int sc[256];
    int tot = run;
    sc[d] = tot;
    __syncthreads();
    for (int s = 1; s < 256; s <<= 1) {
        int v = (d >= s) ? sc[d - s] : 0;
        __syncthreads();
        sc[d] += v;
        __syncthreads();
    }
    int dbase = sc[d] - tot;   // exclusive digit base
    for (int b = 0; b < NBLK; ++b) blockbase[d * NBLK + b] += dbase;
}

// Stable scatter: block processes its RB_SIZE records in 16 ordered rounds of
// 256; rank within (block, digit) from an LDS scan (deterministic).
template <bool FIRST>
__global__ __launch_bounds__(256) void radix_scatter(const int* __restrict__ dstArr,
                                                     const int* __restrict__ srcArr,
                                                     const u64* __restrict__ recIn,
                                                     u64* __restrict__ recOut,
                                                     int* __restrict__ csr_src,
                                                     const int* __restrict__ blockbase,
                                                     int E, int NBLK) {
    __shared__ int dig[256];
    __shared__ int cursor[256];
    __shared__ int gbase[256];
    int tid = threadIdx.x;
    cursor[tid] = 0;
    gbase[tid] = blockbase[tid * NBLK + blockIdx.x];
    int base = blockIdx.x * RB_SIZE;
    __syncthreads();
    for (int r = 0; r < RB_ROUNDS; ++r) {
        int i = base + r * 256 + tid;
        int d = -1;
        u64 rec = 0;
        if (i < E) {
            if (FIRST) {
                int dv = dstArr[i];
                rec = ((u64)(unsigned)srcArr[i] << 32) | (unsigned)dv;
                d = dv & 255;
            } else {
                rec = recIn[i];
                d = (int)((rec >> 8) & 255);
            }
        }
        dig[tid] = d;
        __syncthreads();
        if (d >= 0) {
            int rank = 0, tot = 0;
            const int4* dg4 = (const int4*)dig;
            for (int j = 0; j < 256; j += 4) {
                int4 dd = dg4[j >> 2];
                int m0 = (dd.x == d), m1 = (dd.y == d);
                int m2 = (dd.z == d), m3 = (dd.w == d);
                tot  += m0 + m1 + m2 + m3;
                rank += (j < tid ? m0 : 0) + (j + 1 < tid ? m1 : 0) +
                        (j + 2 < tid ? m2 : 0) + (j + 3 < tid ? m3 : 0);
            }
            int pos = gbase[d] + cursor[d] + rank;
            if (FIRST) recOut[pos] = rec;
            else       csr_src[pos] = (int)(rec >> 32);
            __syncthreads();
            if (rank == tot - 1) cursor[d] += tot;  // unique last occurrence
        } else {
            __syncthreads();
        }
        __syncthreads();
    }
}

// out[M,128] = relu((A (+A2)) @ W[128,128] + bias), fp32 sequential-k FMA chain
// per element (matches sgemm). In-place out==A safe: block stages its own rows.
template <bool FUSE>
__global__ __launch_bounds__(256) void gemm128(const float* __restrict__ A,
                                               const float* __restrict__ A2,
                                               const float* __restrict__ W,
                                               const float* __restrict__ bias,
                                               float* __restrict__ out, int M) {
    __shared__ float Ws[64 * 128];   // one K-half of W: 32 KB
    __shared__ float As[32 * 128];   // 32-row A tile: 16 KB
    int tid = threadIdx.x;
    int row0 = blockIdx.x * 32;

    float4* As4 = (float4*)As;
#pragma unroll
    for (int i = 0; i < 4; ++i) {
        int idx = tid + 256 * i;
        int r = idx >> 5, c = idx & 31;
        int gr = row0 + r;
        float4 v = make_float4(0.f, 0.f, 0.f, 0.f);
        if (gr < M) {
            v = ((const float4*)A)[gr * 32 + c];
            if (FUSE) {
                float4 u = ((const float4*)A2)[gr * 32 + c];
                v.x += u.x; v.y += u.y; v.z += u.z; v.w += u.w;  // agg+h, exact
            }
        }
        As4[idx] = v;
    }

    int tx = tid & 31, ty = tid >> 5;
    float acc[4][4];
#pragma unroll
    for (int r = 0; r < 4; ++r)
#pragma unroll
        for (int c = 0; c < 4; ++c) acc[r][c] = 0.f;

    const float4* W4 = (const float4*)W;
    float4* Ws4 = (float4*)Ws;

    for (int kh = 0; kh < 2; ++kh) {
        __syncthreads();
#pragma unroll
        for (int i = 0; i < 8; ++i)
            Ws4[tid + 256 * i] = W4[kh * 2048 + tid + 256 * i];
        __syncthreads();

        // strictly ascending k; each acc element is one dependent fmaf chain
#pragma unroll 2
        for (int k = 0; k < 64; k += 4) {
            float4 a[4], b[4];
#pragma unroll
            for (int r = 0; r < 4; ++r)
                a[r] = *(const float4*)&As[(ty * 4 + r) * 128 + kh * 64 + k];
#pragma unroll
            for (int kk = 0; kk < 4; ++kk)
                b[kk] = *(const float4*)&Ws[(k + kk) * 128 + tx * 4];
#pragma unroll
            for (int r = 0; r < 4; ++r) {
                acc[r][0] = fmaf(a[r].x, b[0].x, acc[r][0]);
                acc[r][1] = fmaf(a[r].x, b[0].y, acc[r][1]);
                acc[r][2] = fmaf(a[r].x, b[0].z, acc[r][2]);
                acc[r][3] = fmaf(a[r].x, b[0].w, acc[r][3]);
                acc[r][0] = fmaf(a[r].y, b[1].x, acc[r][0]);
                acc[r][1] = fmaf(a[r].y, b[1].y, acc[r][1]);
                acc[r][2] = fmaf(a[r].y, b[1].z, acc[r][2]);
                acc[r][3] = fmaf(a[r].y, b[1].w, acc[r][3]);
                acc[r][0] = fmaf(a[r].z, b[2].x, acc[r][0]);
                acc[r][1] = fmaf(a[r].z, b[2].y, acc[r][1]);
                acc[r][2] = fmaf(a[r].z, b[2].z, acc[r][2]);
                acc[r][3] = fmaf(a[r].z, b[2].w, acc[r][3]);
                acc[r][0] = fmaf(a[r].w, b[3].x, acc[r][0]);
                acc[r][1] = fmaf(a[r].w, b[3].y, acc[r][1]);
                acc[r][2] = fmaf(a[r].w, b[3].z, acc[r][2]);
                acc[r][3] = fmaf(a[r].w, b[3].w, acc[r][3]);
            }
        }
    }

    float4 bv = *(const float4*)&bias[tx * 4];
#pragma unroll
    for (int r = 0; r < 4; ++r) {
        int gr = row0 + ty * 4 + r;
        if (gr < M) {
            float4 o;
            o.x = fmaxf(acc[r][0] + bv.x, 0.f);
            o.y = fmaxf(acc[r][1] + bv.y, 0.f);
            o.z = fmaxf(acc[r][2] + bv.z, 0.f);
            o.w = fmaxf(acc[r][3] + bv.w, 0.f);
            ((float4*)out)[gr * 32 + tx] = o;
        }
    }
}

// Ordered pull aggregation: ONE wave per node (wave-uniform control flow);
// lane holds a float2 feature pair (64 lanes x 8B = full 512B row, 1 VMEM
// instr per edge). Loads staged 8-deep, then adds in strictly ascending edge
// order (== np.add.at); 2 independent fp32 chains per lane.
__global__ __launch_bounds__(256) void aggregate_kernel(const float* __restrict__ h,
                                                        const int* __restrict__ offs,
                                                        const int* __restrict__ csr_src,
                                                        float* __restrict__ agg, int n) {
    int w = (blockIdx.x * 256 + threadIdx.x) >> 6;
    int lane = threadIdx.x & 63;
    if (w >= n) return;
    int beg = offs[w];
    int deg = offs[w + 1] - beg;
    const float2* h2 = (const float2*)h;
    float ax = 0.f, ay = 0.f;
    for (int base = 0; base < deg; base += 64) {
        int sv = (base + lane < deg) ? csr_src[beg + base + lane] : 0;
        int nk = deg - base; if (nk > 64) nk = 64;
        int g = 0;
        for (; g + 8 <= nk; g += 8) {
            float2 r0, r1, r2, r3, r4, r5, r6, r7;
            { int s = __shfl(sv, g + 0); r0 = h2[(size_t)s * 64 + lane]; }
            { int s = __shfl(sv, g + 1); r1 = h2[(size_t)s * 64 + lane]; }
            { int s = __shfl(sv, g + 2); r2 = h2[(size_t)s * 64 + lane]; }
            { int s = __shfl(sv, g + 3); r3 = h2[(size_t)s * 64 + lane]; }
            { int s = __shfl(sv, g + 4); r4 = h2[(size_t)s * 64 + lane]; }
            { int s = __shfl(sv, g + 5); r5 = h2[(size_t)s * 64 + lane]; }
            { int s = __shfl(sv, g + 6); r6 = h2[(size_t)s * 64 + lane]; }
            { int s = __shfl(sv, g + 7); r7 = h2[(size_t)s * 64 + lane]; }
            ax += r0.x; ay += r0.y;
            ax += r1.x; ay += r1.y;
            ax += r2.x; ay += r2.y;
            ax += r3.x; ay += r3.y;
            ax += r4.x; ay += r4.y;
            ax += r5.x; ay += r5.y;
            ax += r6.x; ay += r6.y;
            ax += r7.x; ay += r7.y;
        }
        for (; g < nk; ++g) {
            int s = __shfl(sv, g);
            float2 r = h2[(size_t)s * 64 + lane];
            ax += r.x; ay += r.y;
        }
    }
    ((float2*)agg)[(size_t)w * 64 + lane] = make_float2(ax, ay);
}

// One wave per post. hid[j]: fp32 sequential-k fmaf (matches sgemm).
// Final 64-dot in f64 (unamplified; truth-centered).
__global__ __launch_bounds__(256) void head_kernel(const float* __restrict__ h,
                                                   const int* __restrict__ mask,
                                                   const float* __restrict__ Wo1,
                                                   const float* __restrict__ bo1,
                                                   const float* __restrict__ Wo2,
                                                   const float* __restrict__ bo2,
                                                   float* __restrict__ out, int P) {
    __shared__ float hids[4][64];
    int wid = threadIdx.x >> 6;
    int lane = threadIdx.x & 63;
    int p = blockIdx.x * 4 + wid;
    if (p >= P) return;
    int node = mask[p];
    const float* row = h + (size_t)node * 128;
    float acc = 0.f;
#pragma unroll 4
    for (int k = 0; k < 128; ++k)
        acc = fmaf(row[k], Wo1[k * 64 + lane], acc);
    hids[wid][lane] = fmaxf(acc + bo1[lane], 0.f);
    if (lane == 0) {
        double lg = 0.0;
        for (int j = 0; j < 64; ++j)
            lg = fma((double)hids[wid][j], (double)Wo2[j], lg);
        lg += (double)bo2[0];
        out[p] = (float)(1.0 / (1.0 + exp(-lg)));
    }
}

extern "C" void kernel_launch(void* const* d_in, const int* in_sizes, int n_in,
                              void* d_out, int out_size, void* d_ws, size_t ws_size,
                              hipStream_t stream) {
    const float* NF   = (const float*)d_in[0];
    const int*   EI   = (const int*)d_in[1];
    const int*   MASK = (const int*)d_in[2];
    const float* Wenc = (const float*)d_in[3];
    const float* benc = (const float*)d_in[4];
    const float* W1   = (const float*)d_in[5];
    const float* b1   = (const float*)d_in[6];
    const float* W2   = (const float*)d_in[7];
    const float* b2   = (const float*)d_in[8];
    const float* Wo1  = (const float*)d_in[9];
    const float* bo1  = (const float*)d_in[10];
    const float* Wo2  = (const float*)d_in[11];
    const float* bo2  = (const float*)d_in[12];
    float* out = (float*)d_out;

    const int N = in_sizes[0] / 128;
    const int E = in_sizes[1] / 2;
    const int P = in_sizes[2];

    char* ws = (char*)d_ws;
    size_t off = 0;
    auto alloc = [&](size_t bytes) {
        char* pp = ws + off;
        off += (bytes + 255) & ~(size_t)255;
        return pp;
    };
    float* h       = (float*)alloc((size_t)N * 128 * 4);
    float* agg     = (float*)alloc((size_t)N * 128 * 4);
    int*   offs    = (int*)alloc((size_t)(N + 1) * 4);
    int*   counts  = (int*)alloc((size_t)N * 4);
    int*   csr_src = (int*)alloc((size_t)E * 4);
    const int NBLK = (E + RB_SIZE - 1) / RB_SIZE;
    int*   bh      = (int*)alloc((size_t)256 * NBLK * 4);
    int*   bb      = (int*)alloc((size_t)256 * NBLK * 4);
    int*   bsum    = (int*)alloc(256 * 4);
    int*   bbase   = (int*)alloc(256 * 4);
    // radix tmp records alias h/agg: used strictly before gemm1 writes h.
    u64* rec_a = (u64*)h;     // 12.8 MB <= 25.6 MB
    u64* rec_b = (u64*)agg;

    const int* src = EI;
    const int* dst = EI + E;

    const int nscan = (N + 1023) / 1024;

    // offs (degree histogram + scan)
    zero_kernel<<<(N + 255) / 256, 256, 0, stream>>>(counts, N);
    hist_kernel<<<(E + 255) / 256, 256, 0, stream>>>(dst, counts, E);
    scan_part<<<nscan, 1024, 0, stream>>>(counts, bsum, N);
    scan_tops<<<1, 64, 0, stream>>>(bsum, bbase, nscan, offs, N);
    scan_final<<<nscan, 1024, 0, stream>>>(counts, bbase, offs, N);

    // stable radix sort by dst -> csr_src in (dst, edge-id) order
    radix_hist<true><<<NBLK, 256, 0, stream>>>(dst, nullptr, bh, E, NBLK);
    radix_scan<<<1, 256, 0, stream>>>(bh, bb, NBLK);
    radix_scatter<true><<<NBLK, 256, 0, stream>>>(dst, src, nullptr, rec_a, nullptr, bb, E, NBLK);
    radix_hist<false><<<NBLK, 256, 0, stream>>>(nullptr, rec_a, bh, E, NBLK);
    radix_scan<<<1, 256, 0, stream>>>(bh, bb, NBLK);
    radix_scatter<false><<<NBLK, 256, 0, stream>>>(nullptr, nullptr, rec_a, rec_b, csr_src, bb, E, NBLK);

    int gblocks = (N + 31) / 32;
    int ablocks = (N + 3) / 4;   // one wave per node, 4 waves/block
    gemm128<false><<<gblocks, 256, 0, stream>>>(NF, nullptr, Wenc, benc, h, N);
    aggregate_kernel<<<ablocks, 256, 0, stream>>>(h, offs, csr_src, agg, N);
    gemm128<true><<<gblocks, 256, 0, stream>>>(h, agg, W1, b1, h, N);
    aggregate_kernel<<<ablocks, 256, 0, stream>>>(h, offs, csr_src, agg, N);
    gemm128<true><<<gblocks, 256, 0, stream>>>(h, agg, W2, b2, h, N);
    head_kernel<<<(P + 3) / 4, 256, 0, stream>>>(h, MASK, Wo1, bo1, Wo2, bo2, out, P);
}

// Round 6
// 482.692 us; speedup vs baseline: 2.4672x; 2.4672x over previous
//
#include <hip/hip_runtime.h>
#include <math.h>

// ---------------------------------------------------------------------------
// GCN forward, numerically matched to the numpy float32 reference:
//  - GEMMs: per-element sequential-k fp32 FMA chain (== BLAS sgemm microkernel)
//  - segment_sum: per-feature fp32 adds in ascending-edge order (== np.add.at)
//  - head final dot: f64 (no downstream amplification)
// NUMERICS ARE LOCKED (absmax 1e-13 since round 3): only scheduling/memory
// layout may change between rounds, never the fp32 op order.
//
// CSR build = deterministic stable LSD radix sort by dst (2x8-bit passes),
// payload src. Stability via wave-ballot ranks (lane order = edge order);
// all control scans are hierarchical + parallel (round-5 lesson: a serial
// single-block loop over global memory costs ~300us).
// ---------------------------------------------------------------------------

typedef unsigned long long u64;

#define RB_SIZE   4096
#define RB_ROUNDS 16   // RB_SIZE / 256

__global__ __launch_bounds__(256) void zero_kernel(int* __restrict__ p, int n) {
    int i = blockIdx.x * 256 + threadIdx.x;
    if (i < n) p[i] = 0;
}

__global__ __launch_bounds__(256) void hist_kernel(const int* __restrict__ dst,
                                                   int* __restrict__ counts, int E) {
    int e = blockIdx.x * 256 + threadIdx.x;
    if (e < E) atomicAdd(&counts[dst[e]], 1);
}

// --- hierarchical exclusive scan: in[n] -> out[n] (+ optional total) -------
__global__ __launch_bounds__(1024) void scan_part(const int* __restrict__ in,
                                                  int* __restrict__ bsum, int n) {
    __shared__ int red[1024];
    int i = blockIdx.x * 1024 + threadIdx.x;
    red[threadIdx.x] = (i < n) ? in[i] : 0;
    __syncthreads();
    for (int d = 512; d; d >>= 1) {
        if (threadIdx.x < d) red[threadIdx.x] += red[threadIdx.x + d];
        __syncthreads();
    }
    if (threadIdx.x == 0) bsum[blockIdx.x] = red[0];
}

// one block, parallel Hillis-Steele over nb<=256 block sums
__global__ __launch_bounds__(256) void scan_tops_par(const int* __restrict__ bsum,
                                                     int* __restrict__ bbase, int nb,
                                                     int* __restrict__ total_out) {
    __shared__ int buf[256];
    int tid = threadIdx.x;
    int v = (tid < nb) ? bsum[tid] : 0;
    buf[tid] = v;
    __syncthreads();
    for (int s = 1; s < 256; s <<= 1) {
        int u = (tid >= s) ? buf[tid - s] : 0;
        __syncthreads();
        buf[tid] += u;
        __syncthreads();
    }
    if (tid < nb) bbase[tid] = buf[tid] - v;   // exclusive
    if (tid == 255 && total_out) *total_out = buf[255];
}

__global__ __launch_bounds__(1024) void scan_final(const int* __restrict__ in,
                                                   const int* __restrict__ bbase,
                                                   int* __restrict__ out, int n) {
    __shared__ int buf[1024];
    int tid = threadIdx.x;
    int i = blockIdx.x * 1024 + tid;
    int c = (i < n) ? in[i] : 0;
    buf[tid] = c;
    __syncthreads();
    for (int d = 1; d < 1024; d <<= 1) {
        int v = (tid >= d) ? buf[tid - d] : 0;
        __syncthreads();
        buf[tid] += v;
        __syncthreads();
    }
    if (i < n) out[i] = bbase[blockIdx.x] + buf[tid] - c;
}

// --- radix pass kernels ----------------------------------------------------
// FIRST pass: key = dst & 255, input = raw dst/src arrays, output = u64 records
//             rec = (src << 32) | dst.
// SECOND pass: key = (dst >> 8) & 255 from records, output = src into csr_src.
template <bool FIRST>
__global__ __launch_bounds__(256) void radix_hist(const int* __restrict__ dstArr,
                                                  const u64* __restrict__ recIn,
                                                  int* __restrict__ blockhist,
                                                  int E, int NBLK) {
    __shared__ int cnt[256];
    cnt[threadIdx.x] = 0;
    __syncthreads();
    int base = blockIdx.x * RB_SIZE;
    for (int t = threadIdx.x; t < RB_SIZE; t += 256) {
        int i = base + t;
        if (i < E) {
            int d = FIRST ? (dstArr[i] & 255)
                          : (int)((recIn[i] >> 8) & 255);
            atomicAdd(&cnt[d], 1);
        }
    }
    __syncthreads();
    // digit-major layout [d*NBLK + b]: flat exclusive scan == stable base
    blockhist[threadIdx.x * NBLK + blockIdx.x] = cnt[threadIdx.x];
}

// Stable scatter, ballot-rank version. Block processes RB_SIZE records in 16
// ordered rounds of 256. Within a round: rank among same-digit lanes of the
// wave via 8 ballots (lane order == edge order -> stable); waves stacked in
// wid order via per-(digit,wave) LDS counts; rounds stacked via cursor.
// Fully deterministic, no atomics.
template <bool FIRST>
__global__ __launch_bounds__(256) void radix_scatter(const int* __restrict__ dstArr,
                                                     const int* __restrict__ srcArr,
                                                     const u64* __restrict__ recIn,
                                                     u64* __restrict__ recOut,
                                                     int* __restrict__ csr_src,
                                                     const int* __restrict__ blockbase,
                                                     int E, int NBLK) {
    __shared__ int cursor[256];
    __shared__ int gbase[256];
    __shared__ int cnt[256 * 4];     // [d*4 + wave]
    __shared__ int wbase[256 * 4];
    int tid = threadIdx.x;
    int wid = tid >> 6, lane = tid & 63;
    cursor[tid] = 0;
    gbase[tid] = blockbase[tid * NBLK + blockIdx.x];
    int base = blockIdx.x * RB_SIZE;
    __syncthreads();
    for (int r = 0; r < RB_ROUNDS; ++r) {
        int i = base + r * 256 + tid;
        bool valid = (i < E);
        int d = 0;
        u64 rec = 0;
        if (valid) {
            if (FIRST) {
                int dv = dstArr[i];
                rec = ((u64)(unsigned)srcArr[i] << 32) | (unsigned)dv;
                d = dv & 255;
            } else {
                rec = recIn[i];
                d = (int)((rec >> 8) & 255);
            }
        }
        ((int4*)cnt)[tid] = make_int4(0, 0, 0, 0);   // zero all 1024 counts
        // same-digit lane mask within wave (unconditional ballots)
        u64 mask = ~0ull;
#pragma unroll
        for (int b = 0; b < 8; ++b) {
            int bit = (d >> b) & 1;
            u64 bal = __ballot(bit);
            mask &= bit ? bal : ~bal;
        }
        mask &= __ballot(valid ? 1 : 0);
        int rank = __popcll(mask & (((u64)1 << lane) - 1));
        int wtot = __popcll(mask);
        __syncthreads();                 // cnt zeroed everywhere
        if (valid && rank == 0) cnt[d * 4 + wid] = wtot;  // one writer per (d,w)
        __syncthreads();
        // thread t owns digit t: stack waves onto running cursor
        {
            int run = cursor[tid];
#pragma unroll
            for (int w = 0; w < 4; ++w) {
                wbase[tid * 4 + w] = run;
                run += cnt[tid * 4 + w];
            }
            cursor[tid] = run;
        }
        __syncthreads();
        if (valid) {
            int pos = gbase[d] + wbase[d * 4 + wid] + rank;
            if (FIRST) recOut[pos] = rec;
            else       csr_src[pos] = (int)(rec >> 32);
        }
        __syncthreads();                 // protect wbase/cnt for next round
    }
}

// out[M,128] = relu((A (+A2)) @ W[128,128] + bias), fp32 sequential-k FMA chain
// per element (matches sgemm). In-place out==A safe: block stages its own rows.
template <bool FUSE>
__global__ __launch_bounds__(256) void gemm128(const float* __restrict__ A,
                                               const float* __restrict__ A2,
                                               const float* __restrict__ W,
                                               const float* __restrict__ bias,
                                               float* __restrict__ out, int M) {
    __shared__ float Ws[64 * 128];   // one K-half of W: 32 KB
    __shared__ float As[32 * 128];   // 32-row A tile: 16 KB
    int tid = threadIdx.x;
    int row0 = blockIdx.x * 32;

    float4* As4 = (float4*)As;
#pragma unroll
    for (int i = 0; i < 4; ++i) {
        int idx = tid + 256 * i;
        int r = idx >> 5, c = idx & 31;
        int gr = row0 + r;
        float4 v = make_float4(0.f, 0.f, 0.f, 0.f);
        if (gr < M) {
            v = ((const float4*)A)[gr * 32 + c];
            if (FUSE) {
                float4 u = ((const float4*)A2)[gr * 32 + c];
                v.x += u.x; v.y += u.y; v.z += u.z; v.w += u.w;  // agg+h, exact
            }
        }
        As4[idx] = v;
    }

    int tx = tid & 31, ty = tid >> 5;
    float acc[4][4];
#pragma unroll
    for (int r = 0; r < 4; ++r)
#pragma unroll
        for (int c = 0; c < 4; ++c) acc[r][c] = 0.f;

    const float4* W4 = (const float4*)W;
    float4* Ws4 = (float4*)Ws;

    for (int kh = 0; kh < 2; ++kh) {
        __syncthreads();
#pragma unroll
        for (int i = 0; i < 8; ++i)
            Ws4[tid + 256 * i] = W4[kh * 2048 + tid + 256 * i];
        __syncthreads();

        // strictly ascending k; each acc element is one dependent fmaf chain
#pragma unroll 2
        for (int k = 0; k < 64; k += 4) {
            float4 a[4], b[4];
#pragma unroll
            for (int r = 0; r < 4; ++r)
                a[r] = *(const float4*)&As[(ty * 4 + r) * 128 + kh * 64 + k];
#pragma unroll
            for (int kk = 0; kk < 4; ++kk)
                b[kk] = *(const float4*)&Ws[(k + kk) * 128 + tx * 4];
#pragma unroll
            for (int r = 0; r < 4; ++r) {
                acc[r][0] = fmaf(a[r].x, b[0].x, acc[r][0]);
                acc[r][1] = fmaf(a[r].x, b[0].y, acc[r][1]);
                acc[r][2] = fmaf(a[r].x, b[0].z, acc[r][2]);
                acc[r][3] = fmaf(a[r].x, b[0].w, acc[r][3]);
                acc[r][0] = fmaf(a[r].y, b[1].x, acc[r][0]);
                acc[r][1] = fmaf(a[r].y, b[1].y, acc[r][1]);
                acc[r][2] = fmaf(a[r].y, b[1].z, acc[r][2]);
                acc[r][3] = fmaf(a[r].y, b[1].w, acc[r][3]);
                acc[r][0] = fmaf(a[r].z, b[2].x, acc[r][0]);
                acc[r][1] = fmaf(a[r].z, b[2].y, acc[r][1]);
                acc[r][2] = fmaf(a[r].z, b[2].z, acc[r][2]);
                acc[r][3] = fmaf(a[r].z, b[2].w, acc[r][3]);
                acc[r][0] = fmaf(a[r].w, b[3].x, acc[r][0]);
                acc[r][1] = fmaf(a[r].w, b[3].y, acc[r][1]);
                acc[r][2] = fmaf(a[r].w, b[3].z, acc[r][2]);
                acc[r][3] = fmaf(a[r].w, b[3].w, acc[r][3]);
            }
        }
    }

    float4 bv = *(const float4*)&bias[tx * 4];
#pragma unroll
    for (int r = 0; r < 4; ++r) {
        int gr = row0 + ty * 4 + r;
        if (gr < M) {
            float4 o;
            o.x = fmaxf(acc[r][0] + bv.x, 0.f);
            o.y = fmaxf(acc[r][1] + bv.y, 0.f);
            o.z = fmaxf(acc[r][2] + bv.z, 0.f);
            o.w = fmaxf(acc[r][3] + bv.w, 0.f);
            ((float4*)out)[gr * 32 + tx] = o;
        }
    }
}

// Ordered pull aggregation (round-4 measured variant): one wave = TWO nodes.
// Lanes 0-31 node A, 32-63 node B; each lane holds a float4 feature quad
// (32 lanes x 16B = full 512B row -> one VMEM instr per edge-row). Per-feature
// fp32 add order strictly ascending-edge per node == np.add.at.
__global__ __launch_bounds__(256) void aggregate_kernel(const float* __restrict__ h,
                                                        const int* __restrict__ offs,
                                                        const int* __restrict__ csr_src,
                                                        float* __restrict__ agg, int n) {
    int w = (blockIdx.x * 256 + threadIdx.x) >> 6;   // wave id = node pair
    int lane = threadIdx.x & 63;
    int half = lane >> 5;
    int l32 = lane & 31;
    int node = w * 2 + half;
    bool nvalid = node < n;
    int beg = 0, deg = 0;
    if (nvalid) {
        beg = offs[node];
        deg = offs[node + 1] - beg;
    }
    int mdeg = max(deg, __shfl_xor(deg, 32));  // pair's max degree
    const float4* h4 = (const float4*)h;
    float ax = 0.f, ay = 0.f, az = 0.f, aw = 0.f;
    for (int base = 0; base < mdeg; base += 32) {
        int idx = base + l32;
        int sv = (nvalid && idx < deg) ? csr_src[beg + idx] : 0;
        int nk = mdeg - base; if (nk > 32) nk = 32;
#pragma unroll 4
        for (int j = 0; j < nk; ++j) {
            int s = __shfl(sv, (half << 5) | j);   // own half's j-th source
            if (base + j < deg) {                  // uniform per half
                float4 r = h4[s * 32 + l32];
                ax += r.x; ay += r.y; az += r.z; aw += r.w;
            }
        }
    }
    if (nvalid) {
        float4 o = make_float4(ax, ay, az, aw);
        ((float4*)agg)[(size_t)node * 32 + l32] = o;
    }
}

// One wave per post. hid[j]: fp32 sequential-k fmaf (matches sgemm).
// Final 64-dot in f64 (unamplified; truth-centered).
__global__ __launch_bounds__(256) void head_kernel(const float* __restrict__ h,
                                                   const int* __restrict__ mask,
                                                   const float* __restrict__ Wo1,
                                                   const float* __restrict__ bo1,
                                                   const float* __restrict__ Wo2,
                                                   const float* __restrict__ bo2,
                                                   float* __restrict__ out, int P) {
    __shared__ float hids[4][64];
    int wid = threadIdx.x >> 6;
    int lane = threadIdx.x & 63;
    int p = blockIdx.x * 4 + wid;
    if (p >= P) return;
    int node = mask[p];
    const float* row = h + (size_t)node * 128;
    float acc = 0.f;
#pragma unroll 4
    for (int k = 0; k < 128; ++k)
        acc = fmaf(row[k], Wo1[k * 64 + lane], acc);
    hids[wid][lane] = fmaxf(acc + bo1[lane], 0.f);
    if (lane == 0) {
        double lg = 0.0;
        for (int j = 0; j < 64; ++j)
            lg = fma((double)hids[wid][j], (double)Wo2[j], lg);
        lg += (double)bo2[0];
        out[p] = (float)(1.0 / (1.0 + exp(-lg)));
    }
}

extern "C" void kernel_launch(void* const* d_in, const int* in_sizes, int n_in,
                              void* d_out, int out_size, void* d_ws, size_t ws_size,
                              hipStream_t stream) {
    const float* NF   = (const float*)d_in[0];
    const int*   EI   = (const int*)d_in[1];
    const int*   MASK = (const int*)d_in[2];
    const float* Wenc = (const float*)d_in[3];
    const float* benc = (const float*)d_in[4];
    const float* W1   = (const float*)d_in[5];
    const float* b1   = (const float*)d_in[6];
    const float* W2   = (const float*)d_in[7];
    const float* b2   = (const float*)d_in[8];
    const float* Wo1  = (const float*)d_in[9];
    const float* bo1  = (const float*)d_in[10];
    const float* Wo2  = (const float*)d_in[11];
    const float* bo2  = (const float*)d_in[12];
    float* out = (float*)d_out;

    const int N = in_sizes[0] / 128;
    const int E = in_sizes[1] / 2;
    const int P = in_sizes[2];

    char* ws = (char*)d_ws;
    size_t off = 0;
    auto alloc = [&](size_t bytes) {
        char* pp = ws + off;
        off += (bytes + 255) & ~(size_t)255;
        return pp;
    };
    float* h       = (float*)alloc((size_t)N * 128 * 4);
    float* agg     = (float*)alloc((size_t)N * 128 * 4);
    int*   offs    = (int*)alloc((size_t)(N + 1) * 4);
    int*   counts  = (int*)alloc((size_t)N * 4);
    int*   csr_src = (int*)alloc((size_t)E * 4);
    const int NBLK = (E + RB_SIZE - 1) / RB_SIZE;
    int*   bh      = (int*)alloc((size_t)256 * NBLK * 4);
    int*   bb      = (int*)alloc((size_t)256 * NBLK * 4);
    int*   bsum    = (int*)alloc(256 * 4);
    int*   bbase   = (int*)alloc(256 * 4);
    // radix tmp records alias h/agg: used strictly before gemm1 writes h.
    u64* rec_a = (u64*)h;     // 12.8 MB <= 25.6 MB
    u64* rec_b = (u64*)agg;

    const int* src = EI;
    const int* dst = EI + E;

    // --- offs: degree histogram + hierarchical scan ---
    const int nscan = (N + 1023) / 1024;
    zero_kernel<<<(N + 255) / 256, 256, 0, stream>>>(counts, N);
    hist_kernel<<<(E + 255) / 256, 256, 0, stream>>>(dst, counts, E);
    scan_part<<<nscan, 1024, 0, stream>>>(counts, bsum, N);
    scan_tops_par<<<1, 256, 0, stream>>>(bsum, bbase, nscan, &offs[N]);
    scan_final<<<nscan, 1024, 0, stream>>>(counts, bbase, offs, N);

    // --- stable radix sort by dst -> csr_src in (dst, edge-id) order ---
    const int L = 256 * NBLK;              // flat blockhist length
    const int nscanL = (L + 1023) / 1024;  // <= 256 for E <= 256M
    radix_hist<true><<<NBLK, 256, 0, stream>>>(dst, nullptr, bh, E, NBLK);
    scan_part<<<nscanL, 1024, 0, stream>>>(bh, bsum, L);
    scan_tops_par<<<1, 256, 0, stream>>>(bsum, bbase, nscanL, nullptr);
    scan_final<<<nscanL, 1024, 0, stream>>>(bh, bbase, bb, L);
    radix_scatter<true><<<NBLK, 256, 0, stream>>>(dst, src, nullptr, rec_a, nullptr, bb, E, NBLK);
    radix_hist<false><<<NBLK, 256, 0, stream>>>(nullptr, rec_a, bh, E, NBLK);
    scan_part<<<nscanL, 1024, 0, stream>>>(bh, bsum, L);
    scan_tops_par<<<1, 256, 0, stream>>>(bsum, bbase, nscanL, nullptr);
    scan_final<<<nscanL, 1024, 0, stream>>>(bh, bbase, bb, L);
    radix_scatter<false><<<NBLK, 256, 0, stream>>>(nullptr, nullptr, rec_a, rec_b, csr_src, bb, E, NBLK);

    int gblocks = (N + 31) / 32;
    int ablocks = ((N + 1) / 2 + 3) / 4;   // one wave per node pair, 4 waves/block
    gemm128<false><<<gblocks, 256, 0, stream>>>(NF, nullptr, Wenc, benc, h, N);
    aggregate_kernel<<<ablocks, 256, 0, stream>>>(h, offs, csr_src, agg, N);
    gemm128<true><<<gblocks, 256, 0, stream>>>(h, agg, W1, b1, h, N);
    aggregate_kernel<<<ablocks, 256, 0, stream>>>(h, offs, csr_src, agg, N);
    gemm128<true><<<gblocks, 256, 0, stream>>>(h, agg, W2, b2, h, N);
    head_kernel<<<(P + 3) / 4, 256, 0, stream>>>(h, MASK, Wo1, bo1, Wo2, bo2, out, P);
}